// Round 8
// baseline (8803.925 us; speedup 1.0000x reference)
//
#include <hip/hip_runtime.h>
#include <hip/hip_bf16.h>
#include <math.h>

#define S_LEN 512
#define B_SZ  256
#define E_DIM 128
#define HHID  128
#define G4    512   // 4*HH
#define T_TAG 9
#define NR    (S_LEN * B_SZ)   // r = s*256 + b
#define VOCAB 5001

typedef __attribute__((ext_vector_type(8))) short bf16x8;
typedef __attribute__((ext_vector_type(4))) float f32x4;

__device__ __forceinline__ float bf2f(__hip_bfloat16 v) { return __bfloat162float(v); }
__device__ __forceinline__ float scrub0(float v) {       // inf/nan -> 0
    unsigned u = __float_as_uint(v);
    return (((u >> 23) & 0xFFu) == 0xFFu) ? 0.f : v;
}
// branchless fast activations (v_exp_f32 + v_rcp_f32; correct limits at +-inf)
__device__ __forceinline__ float fsig(float x) {
    return __builtin_amdgcn_rcpf(1.f + __expf(-x));
}
__device__ __forceinline__ float ftanh(float x) {
    return 1.f - 2.f * __builtin_amdgcn_rcpf(1.f + __expf(2.f * x));
}
// quad butterfly via ds_swizzle (xor1 / xor2 within each 4-lane quad)
__device__ __forceinline__ float qx1(float v) {
    return __int_as_float(__builtin_amdgcn_ds_swizzle(__float_as_int(v), 0x041F));
}
__device__ __forceinline__ float qx2(float v) {
    return __int_as_float(__builtin_amdgcn_ds_swizzle(__float_as_int(v), 0x081F));
}

// ---- .bss scratch (~670 MB) ----
__device__ __hip_bfloat16 g_emb[VOCAB * E_DIM];
__device__ __hip_bfloat16 g_wih[2][G4 * E_DIM];
__device__ float g_whh[2][G4 * HHID];
__device__ float g_bias[2][G4];
__device__ float g_wout[T_TAG * 256];
__device__ float g_bout[T_TAG];
__device__ float g_trans[T_TAG * T_TAG];
__device__ float g_start[T_TAG];
__device__ float g_end[T_TAG];
__device__ float g_maskf[B_SZ * S_LEN];
__device__ float g_em[(long)NR * T_TAG];                  // summed f+b+bout
__device__ __align__(16) float g_hs[2][(long)NR * HHID];  // 2 x 67 MB
__device__ __align__(16) float g_pre_f[(long)NR * G4];    // 256 MB
__device__ __align__(16) float g_pre_b[(long)NR * G4];    // 256 MB

// -------------------------------------------------------------------------
__global__ __launch_bounds__(256) void fill_out(float* out, int n) {
    const int i = blockIdx.x * 256 + threadIdx.x;
    if (i < n) out[i] = 0.f;
}

// -------------------------------------------------------------------------
// Canonicalize inputs (bf16 or fp32 autodetect via mask == all-ones).
// -------------------------------------------------------------------------
__global__ __launch_bounds__(256) void convert_kernel(
    const void* mask, const void* emb,
    const void* wih_f, const void* whh_f, const void* bih_f, const void* bhh_f,
    const void* wih_b, const void* whh_b, const void* bih_b, const void* bhh_b,
    const void* wout, const void* bout, const void* trans,
    const void* startt, const void* endt)
{
    const bool isb = (((const unsigned*)mask)[0] == 0x3F803F80u);
    auto ldf = [&](const void* p, long i) -> float {
        float v = isb ? bf2f(((const __hip_bfloat16*)p)[i]) : ((const float*)p)[i];
        return scrub0(v);
    };
    const long tid0   = (long)blockIdx.x * blockDim.x + threadIdx.x;
    const long stride = (long)gridDim.x * blockDim.x;

    for (long i = tid0; i < (long)VOCAB * E_DIM; i += stride)
        g_emb[i] = __float2bfloat16(ldf(emb, i));
    for (long i = tid0; i < (long)G4 * E_DIM; i += stride) {
        g_wih[0][i] = __float2bfloat16(ldf(wih_f, i));
        g_wih[1][i] = __float2bfloat16(ldf(wih_b, i));
    }
    for (long i = tid0; i < (long)G4 * HHID; i += stride) {
        g_whh[0][i] = ldf(whh_f, i);
        g_whh[1][i] = ldf(whh_b, i);
    }
    for (long i = tid0; i < G4; i += stride) {
        g_bias[0][i] = ldf(bih_f, i) + ldf(bhh_f, i);
        g_bias[1][i] = ldf(bih_b, i) + ldf(bhh_b, i);
    }
    for (long i = tid0; i < T_TAG * 256; i += stride) g_wout[i] = ldf(wout, i);
    for (long i = tid0; i < T_TAG * T_TAG; i += stride) g_trans[i] = ldf(trans, i);
    for (long i = tid0; i < T_TAG; i += stride) {
        g_bout[i]  = ldf(bout, i);
        g_start[i] = ldf(startt, i);
        g_end[i]   = ldf(endt, i);
    }
    for (long i = tid0; i < (long)B_SZ * S_LEN; i += stride)
        g_maskf[i] = ldf(mask, i);
}

// -------------------------------------------------------------------------
// pre[r][g] = emb[x[b][s]] . Wih[g] + bias[g], r = s*256+b. MFMA 16x16x32.
// dir = blockIdx.z.
// -------------------------------------------------------------------------
__global__ __launch_bounds__(256, 4)
void gemm_pre(const int* __restrict__ x)
{
    const int dir = blockIdx.z;
    float* __restrict__ pre = dir ? g_pre_b : g_pre_f;
    const __hip_bfloat16* __restrict__ wih = g_wih[dir];
    const int lane = threadIdx.x & 63;
    const int wv   = threadIdx.x >> 6;
    const int m    = lane & 15;
    const int quad = lane >> 4;
    const int rtile = blockIdx.x * 4 + wv;          // 0..8191
    const int r  = rtile * 16 + m;
    const int s  = r >> 8;
    const int bb = r & 255;
    const int g0 = blockIdx.y * 16;
    const bool x64 = ((x[1] | x[3] | x[5] | x[7]) == 0);
    const int ii = bb * S_LEN + s;
    const int xi = x64 ? x[2 * ii] : x[ii];
    const __hip_bfloat16* arow = g_emb + (long)xi * E_DIM + quad * 8;
    const __hip_bfloat16* brow = wih + (long)(g0 + m) * E_DIM + quad * 8;

    f32x4 acc = {0.f, 0.f, 0.f, 0.f};
    #pragma unroll
    for (int k0 = 0; k0 < E_DIM; k0 += 32) {
        bf16x8 af = *(const bf16x8*)(arow + k0);
        bf16x8 bf = *(const bf16x8*)(brow + k0);
        acc = __builtin_amdgcn_mfma_f32_16x16x32_bf16(af, bf, acc, 0, 0, 0);
    }
    const float bsum = g_bias[dir][g0 + m];
    const int rbase = rtile * 16 + quad * 4;
    #pragma unroll
    for (int q = 0; q < 4; q++)
        pre[(long)(rbase + q) * G4 + g0 + m] = acc[q] + bsum;
}

// -------------------------------------------------------------------------
// K-split LSTM scan: grid (256 batch, 2 dir), 512 threads.
// Thread (u = t>>2, kq = t&3) computes all 4 gates of hidden unit u over
// K-slice [kq*32, kq*32+32). Quad butterfly (ds_swizzle) completes the dots;
// every quad lane then holds all 4 preacts -> in-thread c/h update (c is
// replicated x4, identical fp32). Double-buffered h -> ONE barrier/step.
// h written to g_hs (global) for the bulk emission pass.
// Gate g of unit u at index g*128+u (torch order i,f,g,o).
// -------------------------------------------------------------------------
__global__ __launch_bounds__(512, 2) void scan_kernel()
{
    __shared__ __align__(16) float h_buf[2][HHID];

    const int b = blockIdx.x, t = threadIdx.x, dir = blockIdx.y;
    const float* __restrict__ pre = dir ? g_pre_b : g_pre_f;
    float* __restrict__ hs = g_hs[dir];
    const int u  = t >> 2;
    const int kq = t & 3;
    const int gate = kq * 128 + u;   // the gate whose px this lane folds in

    // Whh rows for unit u's 4 gates, K-slice kq: 4 x 8 float4 = 128 VGPRs
    float4 w[4][8];
    #pragma unroll
    for (int j = 0; j < 4; j++) {
        const float4* row = (const float4*)&g_whh[dir][(long)(j * 128 + u) * HHID + kq * 32];
        #pragma unroll
        for (int q = 0; q < 8; q++) w[j][q] = row[q];
    }
    if (t < HHID) { h_buf[0][t] = 0.f; h_buf[1][t] = 0.f; }
    float c = 0.f;
    __syncthreads();

    int se = dir ? (S_LEN - 1) : 0;
    const int step = dir ? -1 : 1;
    float px = pre[((long)se * B_SZ + b) * G4 + gate];

    for (int it = 0; it < S_LEN; it++) {
        const int rd = it & 1, wr = rd ^ 1;
        const int se_next = (it + 1 < S_LEN) ? (se + step) : se;
        const float pxn = pre[((long)se_next * B_SZ + b) * G4 + gate]; // prefetch

        // read h K-slice (bank-staggered by kq -> conflict-free multicast)
        float4 hv[8];
        {
            const float4* hb4 = (const float4*)&h_buf[rd][kq * 32];
            #pragma unroll
            for (int q = 0; q < 8; q++) {
                const int qe = (q + 2 * kq) & 7;
                hv[qe] = hb4[qe];
            }
        }
        float p0 = 0.f, p1 = 0.f, p2 = 0.f, p3 = 0.f;
        #pragma unroll
        for (int q = 0; q < 8; q++) {
            const float4 h4 = hv[q];
            p0 += h4.x*w[0][q].x + h4.y*w[0][q].y + h4.z*w[0][q].z + h4.w*w[0][q].w;
            p1 += h4.x*w[1][q].x + h4.y*w[1][q].y + h4.z*w[1][q].z + h4.w*w[1][q].w;
            p2 += h4.x*w[2][q].x + h4.y*w[2][q].y + h4.z*w[2][q].z + h4.w*w[2][q].w;
            p3 += h4.x*w[3][q].x + h4.y*w[3][q].y + h4.z*w[3][q].z + h4.w*w[3][q].w;
        }
        // fold px into the partial of gate kq (added exactly once per gate)
        p0 += (kq == 0) ? px : 0.f;
        p1 += (kq == 1) ? px : 0.f;
        p2 += (kq == 2) ? px : 0.f;
        p3 += (kq == 3) ? px : 0.f;
        // quad butterfly: all 4 lanes end with all 4 full preacts
        p0 += qx1(p0); p0 += qx2(p0);
        p1 += qx1(p1); p1 += qx2(p1);
        p2 += qx1(p2); p2 += qx2(p2);
        p3 += qx1(p3); p3 += qx2(p3);

        const float gi = fsig(p0), gf = fsig(p1), gg = ftanh(p2), go = fsig(p3);
        c = gf * c + gi * gg;
        const float h = go * ftanh(c);
        if (kq == 0) {
            h_buf[wr][u] = h;
            hs[((long)se * B_SZ + b) * HHID + u] = h;
        }
        __syncthreads();
        px = pxn;
        se = se_next;
    }
}

// -------------------------------------------------------------------------
// Bulk emission: em[r][j] = bout[j] + hf[r].Wout[j,:128] + hb[r].Wout[j,128:]
// One thread per r. Memory-bound (134 MB hs read).
// -------------------------------------------------------------------------
__global__ __launch_bounds__(256, 4) void emission_kernel()
{
    __shared__ __align__(16) float Wsh[T_TAG][260];   // 256 + pad
    __shared__ float bo[T_TAG];
    const int tid = threadIdx.x;
    for (int i = tid; i < T_TAG * 256; i += 256) Wsh[i >> 8][i & 255] = g_wout[i];
    if (tid < T_TAG) bo[tid] = g_bout[tid];
    __syncthreads();

    const long r = (long)blockIdx.x * 256 + tid;
    const float4* hf4 = (const float4*)&g_hs[0][r * HHID];
    const float4* hb4 = (const float4*)&g_hs[1][r * HHID];

    float acc[T_TAG];
    #pragma unroll
    for (int j = 0; j < T_TAG; j++) acc[j] = bo[j];
    for (int q = 0; q < 32; q++) {
        const float4 hv = hf4[q];
        #pragma unroll
        for (int j = 0; j < T_TAG; j++) {
            const float4 wv = *(const float4*)&Wsh[j][4 * q];
            acc[j] += hv.x*wv.x + hv.y*wv.y + hv.z*wv.z + hv.w*wv.w;
        }
    }
    for (int q = 0; q < 32; q++) {
        const float4 hv = hb4[q];
        #pragma unroll
        for (int j = 0; j < T_TAG; j++) {
            const float4 wv = *(const float4*)&Wsh[j][128 + 4 * q];
            acc[j] += hv.x*wv.x + hv.y*wv.y + hv.z*wv.z + hv.w*wv.w;
        }
    }
    #pragma unroll
    for (int j = 0; j < T_TAG; j++) g_em[r * T_TAG + j] = scrub0(acc[j]);
}

// -------------------------------------------------------------------------
// Viterbi: 1 wave per batch element (lanes 0..8 = tags), score broadcast via
// parity LDS. Strict-> argmax = jnp first-max. FP32 out: tags [b*512+s],
// best_score [131072+b]. g_em already includes bout.
// -------------------------------------------------------------------------
__global__ __launch_bounds__(256, 2)
void viterbi_kernel(float* __restrict__ out, int out_size)
{
    __shared__ float sc[2][4][16];
    __shared__ unsigned char bp[4][S_LEN][T_TAG];
    const int wid  = threadIdx.x >> 6;
    const int lane = threadIdx.x & 63;
    const int b  = blockIdx.x * 4 + wid;
    const int jj = (lane < T_TAG) ? lane : 0;

    float tcol[T_TAG];
    #pragma unroll
    for (int i = 0; i < T_TAG; i++) tcol[i] = g_trans[i * T_TAG + jj];

    float score[T_TAG];
    {
        const float m0 = g_maskf[b * S_LEN + 0];
        #pragma unroll
        for (int i = 0; i < T_TAG; i++)
            score[i] = g_start[i] + g_em[(long)b * T_TAG + i] * m0;
    }
    float e = g_em[((long)1 * B_SZ + b) * T_TAG + jj];
    float m = g_maskf[b * S_LEN + 1];

    for (int s = 1; s < S_LEN; s++) {
        float en = 0.f, mn = 0.f;
        if (s + 1 < S_LEN) {   // prefetch next step
            en = g_em[((long)(s + 1) * B_SZ + b) * T_TAG + jj];
            mn = g_maskf[b * S_LEN + s + 1];
        }
        float best = score[0] + tcol[0];
        int arg = 0;
        #pragma unroll
        for (int i = 1; i < T_TAG; i++) {
            const float cnd = score[i] + tcol[i];
            if (cnd > best) { best = cnd; arg = i; }
        }
        float ns; int nbp;
        if (m > 0.f) { ns = best + e * m; nbp = arg; }
        else         { ns = score[jj];    nbp = jj;  }
        if (lane < T_TAG) bp[wid][s][jj] = (unsigned char)nbp;
        if (lane < 16) sc[s & 1][wid][lane] = ns;
        __syncthreads();
        #pragma unroll
        for (int i = 0; i < T_TAG; i++) score[i] = sc[s & 1][wid][i];
        e = en; m = mn;
    }
    #pragma unroll
    for (int i = 0; i < T_TAG; i++) score[i] += g_end[i];

    __syncthreads();

    if (lane == 0) {
        float bs = score[0]; int last = 0;
        #pragma unroll
        for (int i = 1; i < T_TAG; i++)
            if (score[i] > bs) { bs = score[i]; last = i; }
        {
            const unsigned u = __float_as_uint(bs);
            if (((u >> 23) & 0xFFu) == 0xFFu) bs = -100.f;
        }
        if ((long)B_SZ * S_LEN + b < out_size)
            out[(long)B_SZ * S_LEN + b] = bs;
        int tag = last;
        if (tag < 0) tag = 0; if (tag > 8) tag = 8;
        out[(long)b * S_LEN + (S_LEN - 1)] = (float)tag;
        for (int s2 = S_LEN - 1; s2 >= 1; s2--) {
            tag = bp[wid][s2][tag];
            if (tag < 0) tag = 0; if (tag > 8) tag = 8;
            out[(long)b * S_LEN + (s2 - 1)] = (float)tag;
        }
    }
}

// -------------------------------------------------------------------------
extern "C" void kernel_launch(void* const* d_in, const int* in_sizes, int n_in,
                              void* d_out, int out_size, void* d_ws, size_t ws_size,
                              hipStream_t stream) {
    const int* x = (const int*)d_in[0];
    float* out = (float*)d_out;

    fill_out<<<(out_size + 255) / 256, 256, 0, stream>>>(out, out_size);
    convert_kernel<<<512, 256, 0, stream>>>(
        d_in[1], d_in[2], d_in[3], d_in[4], d_in[5], d_in[6],
        d_in[7], d_in[8], d_in[9], d_in[10], d_in[11], d_in[12],
        d_in[13], d_in[14], d_in[15]);
    gemm_pre<<<dim3(2048, 32, 2), 256, 0, stream>>>(x);
    scan_kernel<<<dim3(256, 2), 512, 0, stream>>>();
    emission_kernel<<<512, 256, 0, stream>>>();
    viterbi_kernel<<<64, 256, 0, stream>>>(out, out_size);
}

// Round 9
// 1692.010 us; speedup vs baseline: 5.2032x; 5.2032x over previous
//
#include <hip/hip_runtime.h>
#include <hip/hip_bf16.h>
#include <math.h>

#define S_LEN 512
#define B_SZ  256
#define E_DIM 128
#define HHID  128
#define G4    512   // 4*HH
#define T_TAG 9
#define NR    (S_LEN * B_SZ)   // r = s*256 + b
#define VOCAB 5001
#define APITCH 20    // act LDS [n'][m] pitch in words (80 B -> 16B-aligned rows)
#define HPITCH 136   // h LDS row pitch in bf16 units (128+8: bank stagger)

typedef __attribute__((ext_vector_type(8))) short bf16x8;
typedef __attribute__((ext_vector_type(4))) float f32x4;

__device__ __forceinline__ float bf2f(__hip_bfloat16 v) { return __bfloat162float(v); }
__device__ __forceinline__ float scrub0(float v) {       // inf/nan -> 0
    unsigned u = __float_as_uint(v);
    return (((u >> 23) & 0xFFu) == 0xFFu) ? 0.f : v;
}
__device__ __forceinline__ float frcp(float x) { return __builtin_amdgcn_rcpf(x); }
__device__ __forceinline__ float ftanh(float x) {
    return 1.f - 2.f * frcp(1.f + __expf(2.f * x));
}

// ---- .bss scratch ----
__device__ __hip_bfloat16 g_emb[VOCAB * E_DIM];
__device__ __hip_bfloat16 g_wih[2][G4 * E_DIM];    // rows permuted: n' = 4u+g
__device__ __hip_bfloat16 g_whh2[2][G4 * HHID];    // rows permuted: n' = 4u+g
__device__ float g_bias[2][G4];                    // permuted
__device__ float g_wout[T_TAG * 256];
__device__ float g_bout[T_TAG];
__device__ float g_trans[T_TAG * T_TAG];
__device__ float g_start[T_TAG];
__device__ float g_end[T_TAG];
__device__ float g_maskf[B_SZ * S_LEN];
__device__ float g_em[(long)NR * T_TAG];
__device__ __align__(16) float g_hs[2][(long)NR * HHID];  // 2 x 67 MB
__device__ __align__(16) float g_pre_f[(long)NR * G4];    // 256 MB (fragment order)
__device__ __align__(16) float g_pre_b[(long)NR * G4];    // 256 MB

// -------------------------------------------------------------------------
__global__ __launch_bounds__(256) void fill_out(float* out, int n) {
    const int i = blockIdx.x * 256 + threadIdx.x;
    if (i < n) out[i] = 0.f;
}

// -------------------------------------------------------------------------
// Canonicalize inputs (bf16/fp32 autodetect via mask). Gate permutation:
// column n' = 4u+g  <->  original torch gate row g*128+u.
// -------------------------------------------------------------------------
__global__ __launch_bounds__(256) void convert_kernel(
    const void* mask, const void* emb,
    const void* wih_f, const void* whh_f, const void* bih_f, const void* bhh_f,
    const void* wih_b, const void* whh_b, const void* bih_b, const void* bhh_b,
    const void* wout, const void* bout, const void* trans,
    const void* startt, const void* endt)
{
    const bool isb = (((const unsigned*)mask)[0] == 0x3F803F80u);
    auto ldf = [&](const void* p, long i) -> float {
        float v = isb ? bf2f(((const __hip_bfloat16*)p)[i]) : ((const float*)p)[i];
        return scrub0(v);
    };
    const long tid0   = (long)blockIdx.x * blockDim.x + threadIdx.x;
    const long stride = (long)gridDim.x * blockDim.x;

    for (long i = tid0; i < (long)VOCAB * E_DIM; i += stride)
        g_emb[i] = __float2bfloat16(ldf(emb, i));
    for (long i = tid0; i < (long)G4 * E_DIM; i += stride) {
        const int np = (int)(i >> 7), e = (int)(i & 127);
        const int g = np & 3, u = np >> 2;
        const long src = (long)(g * 128 + u) * E_DIM + e;
        g_wih[0][i] = __float2bfloat16(ldf(wih_f, src));
        g_wih[1][i] = __float2bfloat16(ldf(wih_b, src));
    }
    for (long i = tid0; i < (long)G4 * HHID; i += stride) {
        const int np = (int)(i >> 7), k = (int)(i & 127);
        const int g = np & 3, u = np >> 2;
        const long src = (long)(g * 128 + u) * HHID + k;
        g_whh2[0][i] = __float2bfloat16(ldf(whh_f, src));
        g_whh2[1][i] = __float2bfloat16(ldf(whh_b, src));
    }
    for (long i = tid0; i < G4; i += stride) {
        const int g = (int)i & 3, u = (int)i >> 2;
        const long src = g * 128 + u;
        g_bias[0][i] = ldf(bih_f, src) + ldf(bhh_f, src);
        g_bias[1][i] = ldf(bih_b, src) + ldf(bhh_b, src);
    }
    for (long i = tid0; i < T_TAG * 256; i += stride) g_wout[i] = ldf(wout, i);
    for (long i = tid0; i < T_TAG * T_TAG; i += stride) g_trans[i] = ldf(trans, i);
    for (long i = tid0; i < T_TAG; i += stride) {
        g_bout[i]  = ldf(bout, i);
        g_start[i] = ldf(startt, i);
        g_end[i]   = ldf(endt, i);
    }
    for (long i = tid0; i < (long)B_SZ * S_LEN; i += stride)
        g_maskf[i] = ldf(mask, i);
}

// -------------------------------------------------------------------------
// pre GEMM: MFMA 16x16x32, K=128. Stores RAW D-fragments + bias in MFMA
// fragment order: preT[((rtile*32 + gt)*64 + lane)] as float4 —
// rtile = s*16 + bg, m = lane&15 (batch within), n = gt*16 + lane&15.
// -------------------------------------------------------------------------
__global__ __launch_bounds__(256, 4)
void gemm_pre(const int* __restrict__ x)
{
    const int dir = blockIdx.z;
    float4* __restrict__ pre = (float4*)(dir ? g_pre_b : g_pre_f);
    const __hip_bfloat16* __restrict__ wih = g_wih[dir];
    const int lane = threadIdx.x & 63;
    const int wv   = threadIdx.x >> 6;
    const int m    = lane & 15;
    const int quad = lane >> 4;
    const int rtile = blockIdx.x * 4 + wv;          // 0..8191 = s*16+bg
    const int r  = rtile * 16 + m;
    const int s  = r >> 8;
    const int bb = r & 255;
    const int g0 = blockIdx.y * 16;
    const bool x64 = ((x[1] | x[3] | x[5] | x[7]) == 0);
    const int ii = bb * S_LEN + s;
    const int xi = x64 ? x[2 * ii] : x[ii];
    const __hip_bfloat16* arow = g_emb + (long)xi * E_DIM + quad * 8;
    const __hip_bfloat16* brow = wih + (long)(g0 + m) * E_DIM + quad * 8;

    f32x4 acc = {0.f, 0.f, 0.f, 0.f};
    #pragma unroll
    for (int k0 = 0; k0 < E_DIM; k0 += 32) {
        bf16x8 af = *(const bf16x8*)(arow + k0);
        bf16x8 bf = *(const bf16x8*)(brow + k0);
        acc = __builtin_amdgcn_mfma_f32_16x16x32_bf16(af, bf, acc, 0, 0, 0);
    }
    const float bsum = g_bias[dir][g0 + m];
    float4 st = make_float4(acc[0] + bsum, acc[1] + bsum, acc[2] + bsum, acc[3] + bsum);
    pre[((long)rtile * 32 + blockIdx.y) * 64 + lane] = st;
}

// -------------------------------------------------------------------------
// MFMA recurrence scan: grid (16 bg, 2 dir), 512 thr. Per step:
// G[16m x 512n'] = (h_hi + h_lo)[16x128] @ Whh'^T + pre   (256 MFMA/block)
// B-frags persistent in VGPRs (64); A hi/lo from LDS; D -> activation ->
// act LDS [n'][m] -> c-update threads (m=tid&15, u4=tid>>4) own c,h.
// Gates interleaved n'=4u+g -> the 4 gates of unit u are n' 4u..4u+3.
// -------------------------------------------------------------------------
__global__ __launch_bounds__(512, 1) void scan_mfma()
{
    __shared__ __align__(16) float act3[G4 * APITCH];            // 40 KB
    __shared__ __align__(16) unsigned short h_hi[16 * HPITCH];   // 4.25 KB
    __shared__ __align__(16) unsigned short h_lo[16 * HPITCH];

    const int bg = blockIdx.x, dir = blockIdx.y;
    const int tid = threadIdx.x;
    const int lane = tid & 63, wv = tid >> 6;
    const int m16 = lane & 15, quad = lane >> 4;
    const float4* __restrict__ preT = (const float4*)(dir ? g_pre_b : g_pre_f);
    float* __restrict__ hs = g_hs[dir];

    // persistent B fragments: 4 n-tiles x 4 k-steps x 4 VGPR = 64 VGPRs
    bf16x8 B[4][4];
    #pragma unroll
    for (int t = 0; t < 4; t++) {
        const int np = (wv * 4 + t) * 16 + m16;
        #pragma unroll
        for (int kk = 0; kk < 4; kk++)
            B[t][kk] = *(const bf16x8*)&g_whh2[dir][(long)np * HHID + kk * 32 + quad * 8];
    }
    for (int i = tid; i < 16 * HPITCH; i += 512) { h_hi[i] = 0; h_lo[i] = 0; }
    float c[4] = {0.f, 0.f, 0.f, 0.f};
    const int cm = tid & 15, cu4 = tid >> 4;   // c-update coords
    __syncthreads();

    int se = dir ? (S_LEN - 1) : 0;
    const int step = dir ? -1 : 1;
    const int g = lane & 3;                     // gate type of this lane's n'
    const float asc = (g == 2) ? 2.f : -1.f;

    float4 px[4], pxn[4];
    #pragma unroll
    for (int t = 0; t < 4; t++)
        px[t] = preT[((long)(se * 16 + bg) * 32 + wv * 4 + t) * 64 + lane];

    for (int it = 0; it < S_LEN; it++) {
        const int se_next = (it + 1 < S_LEN) ? (se + step) : se;
        #pragma unroll
        for (int t = 0; t < 4; t++)     // prefetch next step's pre fragments
            pxn[t] = preT[((long)(se_next * 16 + bg) * 32 + wv * 4 + t) * 64 + lane];

        // A fragments (hi/lo) from LDS
        bf16x8 Ah[4], Al[4];
        #pragma unroll
        for (int kk = 0; kk < 4; kk++) {
            Ah[kk] = *(const bf16x8*)&h_hi[m16 * HPITCH + kk * 32 + quad * 8];
            Al[kk] = *(const bf16x8*)&h_lo[m16 * HPITCH + kk * 32 + quad * 8];
        }
        f32x4 acc[4];
        #pragma unroll
        for (int t = 0; t < 4; t++) {
            acc[t] = (f32x4){px[t].x, px[t].y, px[t].z, px[t].w};
            #pragma unroll
            for (int kk = 0; kk < 4; kk++) {
                acc[t] = __builtin_amdgcn_mfma_f32_16x16x32_bf16(Ah[kk], B[t][kk], acc[t], 0, 0, 0);
                acc[t] = __builtin_amdgcn_mfma_f32_16x16x32_bf16(Al[kk], B[t][kk], acc[t], 0, 0, 0);
            }
        }
        // activation (sig for i,f,o; tanh for g) + store to act LDS [n'][m]
        #pragma unroll
        for (int t = 0; t < 4; t++) {
            float4 av;
            float r0 = frcp(1.f + __expf(asc * acc[t][0]));
            float r1 = frcp(1.f + __expf(asc * acc[t][1]));
            float r2 = frcp(1.f + __expf(asc * acc[t][2]));
            float r3 = frcp(1.f + __expf(asc * acc[t][3]));
            if (g == 2) { av.x = 1.f-2.f*r0; av.y = 1.f-2.f*r1; av.z = 1.f-2.f*r2; av.w = 1.f-2.f*r3; }
            else        { av.x = r0; av.y = r1; av.z = r2; av.w = r3; }
            const int np = (wv * 4 + t) * 16 + m16;
            *(float4*)&act3[np * APITCH + quad * 4] = av;
        }
        __syncthreads();                                  // bar1: act visible

        // c-update: thread owns (m=cm, units cu4*4..+3)
        float hv[4];
        #pragma unroll
        for (int uu = 0; uu < 4; uu++) {
            const int n0 = (cu4 * 4 + uu) * 4;
            const float iv = act3[(n0 + 0) * APITCH + cm];
            const float fv = act3[(n0 + 1) * APITCH + cm];
            const float gv = act3[(n0 + 2) * APITCH + cm];
            const float ov = act3[(n0 + 3) * APITCH + cm];
            c[uu] = fv * c[uu] + iv * gv;
            hv[uu] = ov * ftanh(c[uu]);
        }
        // hi/lo bf16 split (truncation; lo captures the remainder)
        unsigned hb[4], lb[4];
        #pragma unroll
        for (int uu = 0; uu < 4; uu++) {
            const unsigned ub = __float_as_uint(hv[uu]);
            hb[uu] = ub >> 16;
            const float hif = __uint_as_float(ub & 0xFFFF0000u);
            lb[uu] = __float_as_uint(hv[uu] - hif) >> 16;
        }
        *(uint2*)&h_hi[cm * HPITCH + cu4 * 4] =
            make_uint2(hb[0] | (hb[1] << 16), hb[2] | (hb[3] << 16));
        *(uint2*)&h_lo[cm * HPITCH + cu4 * 4] =
            make_uint2(lb[0] | (lb[1] << 16), lb[2] | (lb[3] << 16));
        *(float4*)&hs[((long)se * B_SZ + bg * 16 + cm) * HHID + cu4 * 4] =
            make_float4(hv[0], hv[1], hv[2], hv[3]);
        __syncthreads();                                  // bar2: h visible

        #pragma unroll
        for (int t = 0; t < 4; t++) px[t] = pxn[t];
        se = se_next;
    }
}

// -------------------------------------------------------------------------
// Bulk emission: em[r][j] = bout[j] + hf[r].Wout[j,:128] + hb[r].Wout[j,128:]
// -------------------------------------------------------------------------
__global__ __launch_bounds__(256, 4) void emission_kernel()
{
    __shared__ __align__(16) float Wsh[T_TAG][260];
    __shared__ float bo[T_TAG];
    const int tid = threadIdx.x;
    for (int i = tid; i < T_TAG * 256; i += 256) Wsh[i >> 8][i & 255] = g_wout[i];
    if (tid < T_TAG) bo[tid] = g_bout[tid];
    __syncthreads();

    const long r = (long)blockIdx.x * 256 + tid;
    const float4* hf4 = (const float4*)&g_hs[0][r * HHID];
    const float4* hb4 = (const float4*)&g_hs[1][r * HHID];

    float acc[T_TAG];
    #pragma unroll
    for (int j = 0; j < T_TAG; j++) acc[j] = bo[j];
    for (int q = 0; q < 32; q++) {
        const float4 hv = hf4[q];
        #pragma unroll
        for (int j = 0; j < T_TAG; j++) {
            const float4 wv = *(const float4*)&Wsh[j][4 * q];
            acc[j] += hv.x*wv.x + hv.y*wv.y + hv.z*wv.z + hv.w*wv.w;
        }
    }
    for (int q = 0; q < 32; q++) {
        const float4 hv = hb4[q];
        #pragma unroll
        for (int j = 0; j < T_TAG; j++) {
            const float4 wv = *(const float4*)&Wsh[j][128 + 4 * q];
            acc[j] += hv.x*wv.x + hv.y*wv.y + hv.z*wv.z + hv.w*wv.w;
        }
    }
    #pragma unroll
    for (int j = 0; j < T_TAG; j++) g_em[r * T_TAG + j] = scrub0(acc[j]);
}

// -------------------------------------------------------------------------
// Viterbi (unchanged from R6/R7 passing version).
// -------------------------------------------------------------------------
__global__ __launch_bounds__(256, 2)
void viterbi_kernel(float* __restrict__ out, int out_size)
{
    __shared__ float sc[2][4][16];
    __shared__ unsigned char bp[4][S_LEN][T_TAG];
    const int wid  = threadIdx.x >> 6;
    const int lane = threadIdx.x & 63;
    const int b  = blockIdx.x * 4 + wid;
    const int jj = (lane < T_TAG) ? lane : 0;

    float tcol[T_TAG];
    #pragma unroll
    for (int i = 0; i < T_TAG; i++) tcol[i] = g_trans[i * T_TAG + jj];

    float score[T_TAG];
    {
        const float m0 = g_maskf[b * S_LEN + 0];
        #pragma unroll
        for (int i = 0; i < T_TAG; i++)
            score[i] = g_start[i] + g_em[(long)b * T_TAG + i] * m0;
    }
    float e = g_em[((long)1 * B_SZ + b) * T_TAG + jj];
    float m = g_maskf[b * S_LEN + 1];

    for (int s = 1; s < S_LEN; s++) {
        float en = 0.f, mn = 0.f;
        if (s + 1 < S_LEN) {
            en = g_em[((long)(s + 1) * B_SZ + b) * T_TAG + jj];
            mn = g_maskf[b * S_LEN + s + 1];
        }
        float best = score[0] + tcol[0];
        int arg = 0;
        #pragma unroll
        for (int i = 1; i < T_TAG; i++) {
            const float cnd = score[i] + tcol[i];
            if (cnd > best) { best = cnd; arg = i; }
        }
        float ns; int nbp;
        if (m > 0.f) { ns = best + e * m; nbp = arg; }
        else         { ns = score[jj];    nbp = jj;  }
        if (lane < T_TAG) bp[wid][s][jj] = (unsigned char)nbp;
        if (lane < 16) sc[s & 1][wid][lane] = ns;
        __syncthreads();
        #pragma unroll
        for (int i = 0; i < T_TAG; i++) score[i] = sc[s & 1][wid][i];
        e = en; m = mn;
    }
    #pragma unroll
    for (int i = 0; i < T_TAG; i++) score[i] += g_end[i];

    __syncthreads();

    if (lane == 0) {
        float bs = score[0]; int last = 0;
        #pragma unroll
        for (int i = 1; i < T_TAG; i++)
            if (score[i] > bs) { bs = score[i]; last = i; }
        {
            const unsigned u = __float_as_uint(bs);
            if (((u >> 23) & 0xFFu) == 0xFFu) bs = -100.f;
        }
        if ((long)B_SZ * S_LEN + b < out_size)
            out[(long)B_SZ * S_LEN + b] = bs;
        int tag = last;
        if (tag < 0) tag = 0; if (tag > 8) tag = 8;
        out[(long)b * S_LEN + (S_LEN - 1)] = (float)tag;
        for (int s2 = S_LEN - 1; s2 >= 1; s2--) {
            tag = bp[wid][s2][tag];
            if (tag < 0) tag = 0; if (tag > 8) tag = 8;
            out[(long)b * S_LEN + (s2 - 1)] = (float)tag;
        }
    }
}

// -------------------------------------------------------------------------
extern "C" void kernel_launch(void* const* d_in, const int* in_sizes, int n_in,
                              void* d_out, int out_size, void* d_ws, size_t ws_size,
                              hipStream_t stream) {
    const int* x = (const int*)d_in[0];
    float* out = (float*)d_out;

    fill_out<<<(out_size + 255) / 256, 256, 0, stream>>>(out, out_size);
    convert_kernel<<<512, 256, 0, stream>>>(
        d_in[1], d_in[2], d_in[3], d_in[4], d_in[5], d_in[6],
        d_in[7], d_in[8], d_in[9], d_in[10], d_in[11], d_in[12],
        d_in[13], d_in[14], d_in[15]);
    gemm_pre<<<dim3(2048, 32, 2), 256, 0, stream>>>(x);
    scan_mfma<<<dim3(16, 2), 512, 0, stream>>>();
    emission_kernel<<<512, 256, 0, stream>>>();
    viterbi_kernel<<<64, 256, 0, stream>>>(out, out_size);
}

// Round 10
// 1384.621 us; speedup vs baseline: 6.3584x; 1.2220x over previous
//
#include <hip/hip_runtime.h>
#include <hip/hip_bf16.h>
#include <math.h>

#define S_LEN 512
#define B_SZ  256
#define E_DIM 128
#define HHID  128
#define G4    512   // 4*HH
#define T_TAG 9
#define NR    (S_LEN * B_SZ)   // r = s*256 + b
#define VOCAB 5001

typedef __attribute__((ext_vector_type(8))) short bf16x8;
typedef __attribute__((ext_vector_type(4))) float f32x4;

__device__ __forceinline__ float bf2f(__hip_bfloat16 v) { return __bfloat162float(v); }
__device__ __forceinline__ float scrub0(float v) {       // inf/nan -> 0
    unsigned u = __float_as_uint(v);
    return (((u >> 23) & 0xFFu) == 0xFFu) ? 0.f : v;
}
__device__ __forceinline__ float frcp(float x) { return __builtin_amdgcn_rcpf(x); }
__device__ __forceinline__ float fsig(float x) { return frcp(1.f + __expf(-x)); }
__device__ __forceinline__ float ftanh(float x) {
    return 1.f - 2.f * frcp(1.f + __expf(2.f * x));
}

// ---- .bss scratch ----
__device__ __hip_bfloat16 g_emb[VOCAB * E_DIM];
__device__ __hip_bfloat16 g_wih[2][G4 * E_DIM];    // rows permuted: n' = 4u+g
__device__ __hip_bfloat16 g_whh2[2][G4 * HHID];    // rows permuted: n' = 4u+g
__device__ __align__(16) float g_bias[2][G4];      // permuted
__device__ float g_wout[T_TAG * 256];
__device__ float g_bout[T_TAG];
__device__ float g_trans[T_TAG * T_TAG];
__device__ float g_start[T_TAG];
__device__ float g_end[T_TAG];
__device__ float g_maskf[B_SZ * S_LEN];
__device__ float g_em[(long)NR * T_TAG];
__device__ __align__(16) float g_hs[2][(long)NR * HHID];  // [(s*16+bg)*128+u]*16+m
__device__ __align__(16) float g_pre_f[(long)NR * G4];    // 256 MB (fragment order)
__device__ __align__(16) float g_pre_b[(long)NR * G4];    // 256 MB

// -------------------------------------------------------------------------
__global__ __launch_bounds__(256) void fill_out(float* out, int n) {
    const int i = blockIdx.x * 256 + threadIdx.x;
    if (i < n) out[i] = 0.f;
}

// -------------------------------------------------------------------------
// Canonicalize inputs (bf16/fp32 autodetect via mask). Gate permutation:
// row n' = 4u+g  <->  original torch gate row g*128+u.
// -------------------------------------------------------------------------
__global__ __launch_bounds__(256) void convert_kernel(
    const void* mask, const void* emb,
    const void* wih_f, const void* whh_f, const void* bih_f, const void* bhh_f,
    const void* wih_b, const void* whh_b, const void* bih_b, const void* bhh_b,
    const void* wout, const void* bout, const void* trans,
    const void* startt, const void* endt)
{
    const bool isb = (((const unsigned*)mask)[0] == 0x3F803F80u);
    auto ldf = [&](const void* p, long i) -> float {
        float v = isb ? bf2f(((const __hip_bfloat16*)p)[i]) : ((const float*)p)[i];
        return scrub0(v);
    };
    const long tid0   = (long)blockIdx.x * blockDim.x + threadIdx.x;
    const long stride = (long)gridDim.x * blockDim.x;

    for (long i = tid0; i < (long)VOCAB * E_DIM; i += stride)
        g_emb[i] = __float2bfloat16(ldf(emb, i));
    for (long i = tid0; i < (long)G4 * E_DIM; i += stride) {
        const int np = (int)(i >> 7), e = (int)(i & 127);
        const int g = np & 3, u = np >> 2;
        const long src = (long)(g * 128 + u) * E_DIM + e;
        g_wih[0][i] = __float2bfloat16(ldf(wih_f, src));
        g_wih[1][i] = __float2bfloat16(ldf(wih_b, src));
    }
    for (long i = tid0; i < (long)G4 * HHID; i += stride) {
        const int np = (int)(i >> 7), k = (int)(i & 127);
        const int g = np & 3, u = np >> 2;
        const long src = (long)(g * 128 + u) * HHID + k;
        g_whh2[0][i] = __float2bfloat16(ldf(whh_f, src));
        g_whh2[1][i] = __float2bfloat16(ldf(whh_b, src));
    }
    for (long i = tid0; i < G4; i += stride) {
        const int g = (int)i & 3, u = (int)i >> 2;
        const long src = g * 128 + u;
        g_bias[0][i] = ldf(bih_f, src) + ldf(bhh_f, src);
        g_bias[1][i] = ldf(bih_b, src) + ldf(bhh_b, src);
    }
    for (long i = tid0; i < T_TAG * 256; i += stride) g_wout[i] = ldf(wout, i);
    for (long i = tid0; i < T_TAG * T_TAG; i += stride) g_trans[i] = ldf(trans, i);
    for (long i = tid0; i < T_TAG; i += stride) {
        g_bout[i]  = ldf(bout, i);
        g_start[i] = ldf(startt, i);
        g_end[i]   = ldf(endt, i);
    }
    for (long i = tid0; i < (long)B_SZ * S_LEN; i += stride)
        g_maskf[i] = ldf(mask, i);
}

// -------------------------------------------------------------------------
// pre GEMM (transposed fragments): D[n'][m]: A = Wih rows (lane&15 = n_local),
// B = emb rows (lane&15 = m). Lane's float4 = n_local = quad*4+reg, m = lane&15.
// Store raw at preT[(rtile*32 + gt)*64 + lane], rtile = s*16+bg, b = bg*16+m.
// Grid (2048, 8, 2): wave = rtile, 4 gate-tiles each.
// -------------------------------------------------------------------------
__global__ __launch_bounds__(256, 4)
void gemm_pre(const int* __restrict__ x)
{
    const int dir = blockIdx.z;
    float4* __restrict__ pre = (float4*)(dir ? g_pre_b : g_pre_f);
    const __hip_bfloat16* __restrict__ wih = g_wih[dir];
    const int lane = threadIdx.x & 63;
    const int wv   = threadIdx.x >> 6;
    const int m16  = lane & 15;
    const int quad = lane >> 4;
    const int rtile = blockIdx.x * 4 + wv;          // 0..8191 = s*16+bg
    const int s  = rtile >> 4;
    const int bb = (rtile & 15) * 16 + m16;
    const bool x64 = ((x[1] | x[3] | x[5] | x[7]) == 0);
    const int ii = bb * S_LEN + s;
    const int xi = x64 ? x[2 * ii] : x[ii];

    // B fragments: emb row of batch bb (shared across the 4 gate-tiles)
    bf16x8 E[4];
    #pragma unroll
    for (int kk = 0; kk < 4; kk++)
        E[kk] = *(const bf16x8*)&g_emb[(long)xi * E_DIM + kk * 32 + quad * 8];

    #pragma unroll
    for (int t = 0; t < 4; t++) {
        const int gt = blockIdx.y * 4 + t;          // 0..31
        const int np = gt * 16 + m16;               // Wih row (n')
        f32x4 acc = {0.f, 0.f, 0.f, 0.f};
        #pragma unroll
        for (int kk = 0; kk < 4; kk++) {
            bf16x8 wf = *(const bf16x8*)&wih[(long)np * E_DIM + kk * 32 + quad * 8];
            acc = __builtin_amdgcn_mfma_f32_16x16x32_bf16(wf, E[kk], acc, 0, 0, 0);
        }
        const float4 b4 = *(const float4*)&g_bias[dir][gt * 16 + quad * 4];
        float4 st = make_float4(acc[0] + b4.x, acc[1] + b4.y, acc[2] + b4.z, acc[3] + b4.w);
        pre[((long)rtile * 32 + gt) * 64 + lane] = st;
    }
}

// -------------------------------------------------------------------------
// MFMA recurrence scan (transposed): grid (16 bg, 2 dir), 512 thr.
// Per step: G[512n' x 16m] = Whh'[512x128] @ (h_hi+h_lo)[16x128]^T + pre.
// Lane (wv,quad,m16) tile t holds gates i,f,g,o (reg 0..3) of unit
// u = 16wv+4t+quad, batch m = m16 -> c/h update fully in-lane.
// h LDS [buf][hi/lo][kblock=u>>3][m][8] -> b128 reads ~conflict-free.
// ONE barrier per step.
// -------------------------------------------------------------------------
__global__ __launch_bounds__(512, 1) void scan_mfma()
{
    __shared__ __align__(16) unsigned short hB[2][2][16 * 16 * 8];  // 16 KB

    const int bg = blockIdx.x, dir = blockIdx.y;
    const int tid  = threadIdx.x;
    const int lane = tid & 63, wv = tid >> 6;
    const int m16  = lane & 15, quad = lane >> 4;
    const float4* __restrict__ preT = (const float4*)(dir ? g_pre_b : g_pre_f);
    float* __restrict__ hs = g_hs[dir];

    // A fragments: Whh' rows (lane&15 = n_local), persistent: 64 VGPRs
    bf16x8 W[4][4];
    #pragma unroll
    for (int t = 0; t < 4; t++) {
        const int np = (wv * 4 + t) * 16 + m16;
        #pragma unroll
        for (int kk = 0; kk < 4; kk++)
            W[t][kk] = *(const bf16x8*)&g_whh2[dir][(long)np * HHID + kk * 32 + quad * 8];
    }
    for (int i = tid; i < 2 * 2 * 2048; i += 512) ((unsigned short*)hB)[i] = 0;
    float c[4] = {0.f, 0.f, 0.f, 0.f};
    __syncthreads();

    int se = dir ? (S_LEN - 1) : 0;
    const int step = dir ? -1 : 1;

    float4 px[4], pxn[4];
    #pragma unroll
    for (int t = 0; t < 4; t++)
        px[t] = preT[((long)(se * 16 + bg) * 32 + wv * 4 + t) * 64 + lane];

    for (int it = 0; it < S_LEN; it++) {
        const int rd = it & 1, wr = rd ^ 1;
        const int se_next = (it + 1 < S_LEN) ? (se + step) : se;
        #pragma unroll
        for (int t = 0; t < 4; t++)     // prefetch next step's pre fragments
            pxn[t] = preT[((long)(se_next * 16 + bg) * 32 + wv * 4 + t) * 64 + lane];

        // B fragments (h hi/lo): lane&15 = m, k-slice kk*32+quad*8
        bf16x8 Hh[4], Hl[4];
        #pragma unroll
        for (int kk = 0; kk < 4; kk++) {
            const int off = ((kk * 4 + quad) * 16 + m16) * 8;
            Hh[kk] = *(const bf16x8*)&hB[rd][0][off];
            Hl[kk] = *(const bf16x8*)&hB[rd][1][off];
        }
        f32x4 acc[4];
        #pragma unroll
        for (int t = 0; t < 4; t++) {
            acc[t] = (f32x4){px[t].x, px[t].y, px[t].z, px[t].w};
            #pragma unroll
            for (int kk = 0; kk < 4; kk++) {
                acc[t] = __builtin_amdgcn_mfma_f32_16x16x32_bf16(W[t][kk], Hh[kk], acc[t], 0, 0, 0);
                acc[t] = __builtin_amdgcn_mfma_f32_16x16x32_bf16(W[t][kk], Hl[kk], acc[t], 0, 0, 0);
            }
        }
        // in-lane gate activation + c/h update (reg: 0=i 1=f 2=g 3=o)
        #pragma unroll
        for (int t = 0; t < 4; t++) {
            const float iv = fsig(acc[t][0]);
            const float fv = fsig(acc[t][1]);
            const float gv = ftanh(acc[t][2]);
            const float ov = fsig(acc[t][3]);
            c[t] = fv * c[t] + iv * gv;
            const float h = ov * ftanh(c[t]);
            const int u = 16 * wv + 4 * t + quad;
            const unsigned ub = __float_as_uint(h);
            const unsigned hb_ = ub >> 16;
            const float hif = __uint_as_float(ub & 0xFFFF0000u);
            const unsigned lb_ = __float_as_uint(h - hif) >> 16;
            const int ha = (u >> 3) * 128 + m16 * 8 + (u & 7);
            hB[wr][0][ha] = (unsigned short)hb_;
            hB[wr][1][ha] = (unsigned short)lb_;
            hs[((long)(se * 16 + bg) * 128 + u) * 16 + m16] = h;  // coalesced
        }
        __syncthreads();
        #pragma unroll
        for (int t = 0; t < 4; t++) px[t] = pxn[t];
        se = se_next;
    }
}

// -------------------------------------------------------------------------
// Bulk emission from hs2 layout: block = (s,bg) tile [128u x 16m], staged in
// LDS; thread (m, j<9) dots 256-k. em[r*9+j] includes bout.
// -------------------------------------------------------------------------
__global__ __launch_bounds__(256, 4) void emission_kernel()
{
    __shared__ float hfL[2048], hbL[2048];
    __shared__ float Wsh[T_TAG][256];
    __shared__ float bo[T_TAG];
    const int tid = threadIdx.x, blk = blockIdx.x;   // 0..8191 = s*16+bg
    for (int i = tid; i < T_TAG * 256; i += 256) Wsh[i >> 8][i & 255] = g_wout[i];
    if (tid < T_TAG) bo[tid] = g_bout[tid];
    const float* hf = &g_hs[0][(long)blk * 2048];
    const float* hb = &g_hs[1][(long)blk * 2048];
    for (int i = tid; i < 2048; i += 256) { hfL[i] = hf[i]; hbL[i] = hb[i]; }
    __syncthreads();

    const int m = tid & 15, j = tid >> 4;
    if (j < T_TAG) {
        float acc = bo[j];
        #pragma unroll 4
        for (int u = 0; u < 128; u++)
            acc += hfL[u * 16 + m] * Wsh[j][u] + hbL[u * 16 + m] * Wsh[j][128 + u];
        const int r = (blk >> 4) * 256 + (blk & 15) * 16 + m;   // s*256 + b
        g_em[(long)r * T_TAG + j] = scrub0(acc);
    }
}

// -------------------------------------------------------------------------
// Viterbi (unchanged from R9 passing version).
// -------------------------------------------------------------------------
__global__ __launch_bounds__(256, 2)
void viterbi_kernel(float* __restrict__ out, int out_size)
{
    __shared__ float sc[2][4][16];
    __shared__ unsigned char bp[4][S_LEN][T_TAG];
    const int wid  = threadIdx.x >> 6;
    const int lane = threadIdx.x & 63;
    const int b  = blockIdx.x * 4 + wid;
    const int jj = (lane < T_TAG) ? lane : 0;

    float tcol[T_TAG];
    #pragma unroll
    for (int i = 0; i < T_TAG; i++) tcol[i] = g_trans[i * T_TAG + jj];

    float score[T_TAG];
    {
        const float m0 = g_maskf[b * S_LEN + 0];
        #pragma unroll
        for (int i = 0; i < T_TAG; i++)
            score[i] = g_start[i] + g_em[(long)b * T_TAG + i] * m0;
    }
    float e = g_em[((long)1 * B_SZ + b) * T_TAG + jj];
    float m = g_maskf[b * S_LEN + 1];

    for (int s = 1; s < S_LEN; s++) {
        float en = 0.f, mn = 0.f;
        if (s + 1 < S_LEN) {
            en = g_em[((long)(s + 1) * B_SZ + b) * T_TAG + jj];
            mn = g_maskf[b * S_LEN + s + 1];
        }
        float best = score[0] + tcol[0];
        int arg = 0;
        #pragma unroll
        for (int i = 1; i < T_TAG; i++) {
            const float cnd = score[i] + tcol[i];
            if (cnd > best) { best = cnd; arg = i; }
        }
        float ns; int nbp;
        if (m > 0.f) { ns = best + e * m; nbp = arg; }
        else         { ns = score[jj];    nbp = jj;  }
        if (lane < T_TAG) bp[wid][s][jj] = (unsigned char)nbp;
        if (lane < 16) sc[s & 1][wid][lane] = ns;
        __syncthreads();
        #pragma unroll
        for (int i = 0; i < T_TAG; i++) score[i] = sc[s & 1][wid][i];
        e = en; m = mn;
    }
    #pragma unroll
    for (int i = 0; i < T_TAG; i++) score[i] += g_end[i];

    __syncthreads();

    if (lane == 0) {
        float bs = score[0]; int last = 0;
        #pragma unroll
        for (int i = 1; i < T_TAG; i++)
            if (score[i] > bs) { bs = score[i]; last = i; }
        {
            const unsigned u = __float_as_uint(bs);
            if (((u >> 23) & 0xFFu) == 0xFFu) bs = -100.f;
        }
        if ((long)B_SZ * S_LEN + b < out_size)
            out[(long)B_SZ * S_LEN + b] = bs;
        int tag = last;
        if (tag < 0) tag = 0; if (tag > 8) tag = 8;
        out[(long)b * S_LEN + (S_LEN - 1)] = (float)tag;
        for (int s2 = S_LEN - 1; s2 >= 1; s2--) {
            tag = bp[wid][s2][tag];
            if (tag < 0) tag = 0; if (tag > 8) tag = 8;
            out[(long)b * S_LEN + (s2 - 1)] = (float)tag;
        }
    }
}

// -------------------------------------------------------------------------
extern "C" void kernel_launch(void* const* d_in, const int* in_sizes, int n_in,
                              void* d_out, int out_size, void* d_ws, size_t ws_size,
                              hipStream_t stream) {
    const int* x = (const int*)d_in[0];
    float* out = (float*)d_out;

    fill_out<<<(out_size + 255) / 256, 256, 0, stream>>>(out, out_size);
    convert_kernel<<<512, 256, 0, stream>>>(
        d_in[1], d_in[2], d_in[3], d_in[4], d_in[5], d_in[6],
        d_in[7], d_in[8], d_in[9], d_in[10], d_in[11], d_in[12],
        d_in[13], d_in[14], d_in[15]);
    gemm_pre<<<dim3(2048, 8, 2), 256, 0, stream>>>(x);
    scan_mfma<<<dim3(16, 2), 512, 0, stream>>>();
    emission_kernel<<<8192, 256, 0, stream>>>();
    viterbi_kernel<<<64, 256, 0, stream>>>(out, out_size);
}

// Round 11
// 1164.252 us; speedup vs baseline: 7.5619x; 1.1893x over previous
//
#include <hip/hip_runtime.h>
#include <hip/hip_bf16.h>
#include <math.h>

#define S_LEN 512
#define B_SZ  256
#define E_DIM 128
#define HHID  128
#define G4    512   // 4*HH
#define T_TAG 9
#define NR    (S_LEN * B_SZ)   // r = s*256 + b
#define VOCAB 5001

typedef __attribute__((ext_vector_type(8))) short bf16x8;
typedef __attribute__((ext_vector_type(4))) float f32x4;

__device__ __forceinline__ float bf2f(__hip_bfloat16 v) { return __bfloat162float(v); }
__device__ __forceinline__ float scrub0(float v) {       // inf/nan -> 0
    unsigned u = __float_as_uint(v);
    return (((u >> 23) & 0xFFu) == 0xFFu) ? 0.f : v;
}
__device__ __forceinline__ float frcp(float x) { return __builtin_amdgcn_rcpf(x); }
__device__ __forceinline__ float fsig(float x) { return frcp(1.f + __expf(-x)); }
__device__ __forceinline__ float ftanh(float x) {
    return 1.f - 2.f * frcp(1.f + __expf(2.f * x));
}

// ---- .bss scratch (~150 MB; pre buffers deleted) ----
__device__ __hip_bfloat16 g_emb[VOCAB * E_DIM];
__device__ __hip_bfloat16 g_wih[2][G4 * E_DIM];    // rows permuted: n' = 4u+g
__device__ __hip_bfloat16 g_whh2[2][G4 * HHID];    // rows permuted: n' = 4u+g
__device__ __align__(16) float g_bias[2][G4];      // permuted
__device__ float g_wout[T_TAG * 256];
__device__ float g_bout[T_TAG];
__device__ float g_trans[T_TAG * T_TAG];
__device__ float g_start[T_TAG];
__device__ float g_end[T_TAG];
__device__ float g_maskf[B_SZ * S_LEN];
__device__ float g_em[(long)NR * T_TAG];
__device__ __align__(16) float g_hs[2][(long)NR * HHID];  // [(s*16+bg)*128+u]*16+m

// -------------------------------------------------------------------------
__global__ __launch_bounds__(256) void fill_out(float* out, int n) {
    const int i = blockIdx.x * 256 + threadIdx.x;
    if (i < n) out[i] = 0.f;
}

// -------------------------------------------------------------------------
// Canonicalize inputs (bf16/fp32 autodetect via mask). Gate permutation:
// row n' = 4u+g  <->  original torch gate row g*128+u.
// -------------------------------------------------------------------------
__global__ __launch_bounds__(256) void convert_kernel(
    const void* mask, const void* emb,
    const void* wih_f, const void* whh_f, const void* bih_f, const void* bhh_f,
    const void* wih_b, const void* whh_b, const void* bih_b, const void* bhh_b,
    const void* wout, const void* bout, const void* trans,
    const void* startt, const void* endt)
{
    const bool isb = (((const unsigned*)mask)[0] == 0x3F803F80u);
    auto ldf = [&](const void* p, long i) -> float {
        float v = isb ? bf2f(((const __hip_bfloat16*)p)[i]) : ((const float*)p)[i];
        return scrub0(v);
    };
    const long tid0   = (long)blockIdx.x * blockDim.x + threadIdx.x;
    const long stride = (long)gridDim.x * blockDim.x;

    for (long i = tid0; i < (long)VOCAB * E_DIM; i += stride)
        g_emb[i] = __float2bfloat16(ldf(emb, i));
    for (long i = tid0; i < (long)G4 * E_DIM; i += stride) {
        const int np = (int)(i >> 7), e = (int)(i & 127);
        const int g = np & 3, u = np >> 2;
        const long src = (long)(g * 128 + u) * E_DIM + e;
        g_wih[0][i] = __float2bfloat16(ldf(wih_f, src));
        g_wih[1][i] = __float2bfloat16(ldf(wih_b, src));
    }
    for (long i = tid0; i < (long)G4 * HHID; i += stride) {
        const int np = (int)(i >> 7), k = (int)(i & 127);
        const int g = np & 3, u = np >> 2;
        const long src = (long)(g * 128 + u) * HHID + k;
        g_whh2[0][i] = __float2bfloat16(ldf(whh_f, src));
        g_whh2[1][i] = __float2bfloat16(ldf(whh_b, src));
    }
    for (long i = tid0; i < G4; i += stride) {
        const int g = (int)i & 3, u = (int)i >> 2;
        const long src = g * 128 + u;
        g_bias[0][i] = ldf(bih_f, src) + ldf(bhh_f, src);
        g_bias[1][i] = ldf(bih_b, src) + ldf(bhh_b, src);
    }
    for (long i = tid0; i < T_TAG * 256; i += stride) g_wout[i] = ldf(wout, i);
    for (long i = tid0; i < T_TAG * T_TAG; i += stride) g_trans[i] = ldf(trans, i);
    for (long i = tid0; i < T_TAG; i += stride) {
        g_bout[i]  = ldf(bout, i);
        g_start[i] = ldf(startt, i);
        g_end[i]   = ldf(endt, i);
    }
    for (long i = tid0; i < (long)B_SZ * S_LEN; i += stride)
        g_maskf[i] = ldf(mask, i);
}

// -------------------------------------------------------------------------
// Fully fused MFMA scan: grid (16 bg, 2 dir), 512 thr. Per step:
// G[512n' x 16m] = Wih'@emb_rows^T + Whh'@(h_hi+h_lo)^T + bias.
// emb is L2-resident (1.28 MB) -> no HBM streaming. Lane (wv,quad,m16)
// tile t holds gates i,f,g,o (reg 0..3) of unit u=16wv+4t+quad, batch m16
// -> c/h update fully in-lane. ONE barrier per step.
// -------------------------------------------------------------------------
__global__ __launch_bounds__(512, 1) void scan_mfma(const int* __restrict__ x)
{
    __shared__ __align__(16) unsigned short hB[2][2][16 * 16 * 8];  // 16 KB
    __shared__ int xL[S_LEN * 16];                                  // 32 KB

    const int bg = blockIdx.x, dir = blockIdx.y;
    const int tid  = threadIdx.x;
    const int lane = tid & 63, wv = tid >> 6;
    const int m16  = lane & 15, quad = lane >> 4;
    float* __restrict__ hs = g_hs[dir];

    // persistent A fragments: Whh' + Wih' rows (lane&15 = n_local): 128 VGPRs
    bf16x8 W[4][4], V[4][4];
    f32x4 bias4[4];
    #pragma unroll
    for (int t = 0; t < 4; t++) {
        const int np = (wv * 4 + t) * 16 + m16;
        #pragma unroll
        for (int kk = 0; kk < 4; kk++) {
            W[t][kk] = *(const bf16x8*)&g_whh2[dir][(long)np * HHID + kk * 32 + quad * 8];
            V[t][kk] = *(const bf16x8*)&g_wih[dir][(long)np * E_DIM + kk * 32 + quad * 8];
        }
        const int u = 16 * wv + 4 * t + quad;
        const float4 b4 = *(const float4*)&g_bias[dir][4 * u];
        bias4[t] = (f32x4){b4.x, b4.y, b4.z, b4.w};
    }
    {   // stage this block's token indices: xL[s*16+m] = x[bg*16+m][s]
        const bool x64 = ((x[1] | x[3] | x[5] | x[7]) == 0);
        for (int i = tid; i < S_LEN * 16; i += 512) {
            const int s = i >> 4, m = i & 15;
            const int ii = (bg * 16 + m) * S_LEN + s;
            xL[i] = x64 ? x[2 * ii] : x[ii];
        }
    }
    for (int i = tid; i < 2 * 2 * 2048; i += 512) ((unsigned short*)hB)[i] = 0;
    float c[4] = {0.f, 0.f, 0.f, 0.f};
    __syncthreads();

    int se = dir ? (S_LEN - 1) : 0;
    const int step = dir ? -1 : 1;

    // first step's emb B-fragments (lane&15 = m)
    bf16x8 E[4], En[4];
    {
        const int xi = xL[se * 16 + m16];
        #pragma unroll
        for (int kk = 0; kk < 4; kk++)
            E[kk] = *(const bf16x8*)&g_emb[(long)xi * E_DIM + kk * 32 + quad * 8];
    }

    for (int it = 0; it < S_LEN; it++) {
        const int rd = it & 1, wr = rd ^ 1;
        const int se_next = (it + 1 < S_LEN) ? (se + step) : se;
        {   // prefetch next step's emb fragments (L2-resident)
            const int xin = xL[se_next * 16 + m16];
            #pragma unroll
            for (int kk = 0; kk < 4; kk++)
                En[kk] = *(const bf16x8*)&g_emb[(long)xin * E_DIM + kk * 32 + quad * 8];
        }
        // B fragments (h hi/lo) from LDS
        bf16x8 Hh[4], Hl[4];
        #pragma unroll
        for (int kk = 0; kk < 4; kk++) {
            const int off = ((kk * 4 + quad) * 16 + m16) * 8;
            Hh[kk] = *(const bf16x8*)&hB[rd][0][off];
            Hl[kk] = *(const bf16x8*)&hB[rd][1][off];
        }
        f32x4 acc[4];
        #pragma unroll
        for (int t = 0; t < 4; t++) {
            acc[t] = bias4[t];
            #pragma unroll
            for (int kk = 0; kk < 4; kk++)
                acc[t] = __builtin_amdgcn_mfma_f32_16x16x32_bf16(V[t][kk], E[kk], acc[t], 0, 0, 0);
            #pragma unroll
            for (int kk = 0; kk < 4; kk++) {
                acc[t] = __builtin_amdgcn_mfma_f32_16x16x32_bf16(W[t][kk], Hh[kk], acc[t], 0, 0, 0);
                acc[t] = __builtin_amdgcn_mfma_f32_16x16x32_bf16(W[t][kk], Hl[kk], acc[t], 0, 0, 0);
            }
        }
        // in-lane gate activation + c/h update (reg: 0=i 1=f 2=g 3=o)
        #pragma unroll
        for (int t = 0; t < 4; t++) {
            const float iv = fsig(acc[t][0]);
            const float fv = fsig(acc[t][1]);
            const float gv = ftanh(acc[t][2]);
            const float ov = fsig(acc[t][3]);
            c[t] = fv * c[t] + iv * gv;
            const float h = ov * ftanh(c[t]);
            const int u = 16 * wv + 4 * t + quad;
            const unsigned ub = __float_as_uint(h);
            const unsigned hb_ = ub >> 16;
            const float hif = __uint_as_float(ub & 0xFFFF0000u);
            const unsigned lb_ = __float_as_uint(h - hif) >> 16;
            const int ha = (u >> 3) * 128 + m16 * 8 + (u & 7);
            hB[wr][0][ha] = (unsigned short)hb_;
            hB[wr][1][ha] = (unsigned short)lb_;
            hs[((long)(se * 16 + bg) * 128 + u) * 16 + m16] = h;  // coalesced
        }
        __syncthreads();
        #pragma unroll
        for (int kk = 0; kk < 4; kk++) E[kk] = En[kk];
        se = se_next;
    }
}

// -------------------------------------------------------------------------
// Bulk emission from hs layout: block = (s,bg) tile [128u x 16m], staged in
// LDS; thread (m, j<9) dots 256-k. em[r*9+j] includes bout.
// -------------------------------------------------------------------------
__global__ __launch_bounds__(256, 4) void emission_kernel()
{
    __shared__ float hfL[2048], hbL[2048];
    __shared__ float Wsh[T_TAG][256];
    __shared__ float bo[T_TAG];
    const int tid = threadIdx.x, blk = blockIdx.x;   // 0..8191 = s*16+bg
    for (int i = tid; i < T_TAG * 256; i += 256) Wsh[i >> 8][i & 255] = g_wout[i];
    if (tid < T_TAG) bo[tid] = g_bout[tid];
    const float* hf = &g_hs[0][(long)blk * 2048];
    const float* hb = &g_hs[1][(long)blk * 2048];
    for (int i = tid; i < 2048; i += 256) { hfL[i] = hf[i]; hbL[i] = hb[i]; }
    __syncthreads();

    const int m = tid & 15, j = tid >> 4;
    if (j < T_TAG) {
        float acc = bo[j];
        #pragma unroll 4
        for (int u = 0; u < 128; u++)
            acc += hfL[u * 16 + m] * Wsh[j][u] + hbL[u * 16 + m] * Wsh[j][128 + u];
        const int r = (blk >> 4) * 256 + (blk & 15) * 16 + m;   // s*256 + b
        g_em[(long)r * T_TAG + j] = scrub0(acc);
    }
}

// -------------------------------------------------------------------------
// Viterbi (unchanged from R9/R10 passing version).
// -------------------------------------------------------------------------
__global__ __launch_bounds__(256, 2)
void viterbi_kernel(float* __restrict__ out, int out_size)
{
    __shared__ float sc[2][4][16];
    __shared__ unsigned char bp[4][S_LEN][T_TAG];
    const int wid  = threadIdx.x >> 6;
    const int lane = threadIdx.x & 63;
    const int b  = blockIdx.x * 4 + wid;
    const int jj = (lane < T_TAG) ? lane : 0;

    float tcol[T_TAG];
    #pragma unroll
    for (int i = 0; i < T_TAG; i++) tcol[i] = g_trans[i * T_TAG + jj];

    float score[T_TAG];
    {
        const float m0 = g_maskf[b * S_LEN + 0];
        #pragma unroll
        for (int i = 0; i < T_TAG; i++)
            score[i] = g_start[i] + g_em[(long)b * T_TAG + i] * m0;
    }
    float e = g_em[((long)1 * B_SZ + b) * T_TAG + jj];
    float m = g_maskf[b * S_LEN + 1];

    for (int s = 1; s < S_LEN; s++) {
        float en = 0.f, mn = 0.f;
        if (s + 1 < S_LEN) {
            en = g_em[((long)(s + 1) * B_SZ + b) * T_TAG + jj];
            mn = g_maskf[b * S_LEN + s + 1];
        }
        float best = score[0] + tcol[0];
        int arg = 0;
        #pragma unroll
        for (int i = 1; i < T_TAG; i++) {
            const float cnd = score[i] + tcol[i];
            if (cnd > best) { best = cnd; arg = i; }
        }
        float ns; int nbp;
        if (m > 0.f) { ns = best + e * m; nbp = arg; }
        else         { ns = score[jj];    nbp = jj;  }
        if (lane < T_TAG) bp[wid][s][jj] = (unsigned char)nbp;
        if (lane < 16) sc[s & 1][wid][lane] = ns;
        __syncthreads();
        #pragma unroll
        for (int i = 0; i < T_TAG; i++) score[i] = sc[s & 1][wid][i];
        e = en; m = mn;
    }
    #pragma unroll
    for (int i = 0; i < T_TAG; i++) score[i] += g_end[i];

    __syncthreads();

    if (lane == 0) {
        float bs = score[0]; int last = 0;
        #pragma unroll
        for (int i = 1; i < T_TAG; i++)
            if (score[i] > bs) { bs = score[i]; last = i; }
        {
            const unsigned u = __float_as_uint(bs);
            if (((u >> 23) & 0xFFu) == 0xFFu) bs = -100.f;
        }
        if ((long)B_SZ * S_LEN + b < out_size)
            out[(long)B_SZ * S_LEN + b] = bs;
        int tag = last;
        if (tag < 0) tag = 0; if (tag > 8) tag = 8;
        out[(long)b * S_LEN + (S_LEN - 1)] = (float)tag;
        for (int s2 = S_LEN - 1; s2 >= 1; s2--) {
            tag = bp[wid][s2][tag];
            if (tag < 0) tag = 0; if (tag > 8) tag = 8;
            out[(long)b * S_LEN + (s2 - 1)] = (float)tag;
        }
    }
}

// -------------------------------------------------------------------------
extern "C" void kernel_launch(void* const* d_in, const int* in_sizes, int n_in,
                              void* d_out, int out_size, void* d_ws, size_t ws_size,
                              hipStream_t stream) {
    const int* x = (const int*)d_in[0];
    float* out = (float*)d_out;

    fill_out<<<(out_size + 255) / 256, 256, 0, stream>>>(out, out_size);
    convert_kernel<<<512, 256, 0, stream>>>(
        d_in[1], d_in[2], d_in[3], d_in[4], d_in[5], d_in[6],
        d_in[7], d_in[8], d_in[9], d_in[10], d_in[11], d_in[12],
        d_in[13], d_in[14], d_in[15]);
    scan_mfma<<<dim3(16, 2), 512, 0, stream>>>(x);
    emission_kernel<<<8192, 256, 0, stream>>>();
    viterbi_kernel<<<64, 256, 0, stream>>>(out, out_size);
}

// Round 12
// 1132.941 us; speedup vs baseline: 7.7709x; 1.0276x over previous
//
#include <hip/hip_runtime.h>
#include <hip/hip_bf16.h>
#include <math.h>

#define S_LEN 512
#define B_SZ  256
#define E_DIM 128
#define HHID  128
#define G4    512   // 4*HH
#define T_TAG 9
#define NR    (S_LEN * B_SZ)   // r = s*256 + b
#define VOCAB 5001

typedef __attribute__((ext_vector_type(8))) short bf16x8;
typedef __attribute__((ext_vector_type(4))) float f32x4;

__device__ __forceinline__ float bf2f(__hip_bfloat16 v) { return __bfloat162float(v); }
__device__ __forceinline__ float scrub0(float v) {       // inf/nan -> 0
    unsigned u = __float_as_uint(v);
    return (((u >> 23) & 0xFFu) == 0xFFu) ? 0.f : v;
}
__device__ __forceinline__ float frcp(float x) { return __builtin_amdgcn_rcpf(x); }
__device__ __forceinline__ float fsig(float x) { return frcp(1.f + __expf(-x)); }
__device__ __forceinline__ float ftanh(float x) {
    return 1.f - 2.f * frcp(1.f + __expf(2.f * x));
}

// ---- .bss scratch (~150 MB) ----
__device__ __hip_bfloat16 g_emb[VOCAB * E_DIM];
__device__ __hip_bfloat16 g_wih[2][G4 * E_DIM];    // rows permuted: n' = 4u+g
__device__ __hip_bfloat16 g_whh2[2][G4 * HHID];    // rows permuted: n' = 4u+g
__device__ __align__(16) float g_bias[2][G4];      // permuted
__device__ float g_wout[T_TAG * 256];
__device__ float g_bout[T_TAG];
__device__ float g_trans[T_TAG * T_TAG];
__device__ float g_start[T_TAG];
__device__ float g_end[T_TAG];
__device__ float g_maskf[B_SZ * S_LEN];
__device__ float g_em[(long)NR * T_TAG];
__device__ __align__(16) float g_hs[2][(long)NR * HHID];  // [(s*16+bg)*128+u]*16+m

// -------------------------------------------------------------------------
__global__ __launch_bounds__(256) void fill_out(float* out, int n) {
    const int i = blockIdx.x * 256 + threadIdx.x;
    if (i < n) out[i] = 0.f;
}

// -------------------------------------------------------------------------
// Canonicalize inputs (bf16/fp32 autodetect via mask). Gate permutation:
// row n' = 4u+g  <->  original torch gate row g*128+u.
// -------------------------------------------------------------------------
__global__ __launch_bounds__(256) void convert_kernel(
    const void* mask, const void* emb,
    const void* wih_f, const void* whh_f, const void* bih_f, const void* bhh_f,
    const void* wih_b, const void* whh_b, const void* bih_b, const void* bhh_b,
    const void* wout, const void* bout, const void* trans,
    const void* startt, const void* endt)
{
    const bool isb = (((const unsigned*)mask)[0] == 0x3F803F80u);
    auto ldf = [&](const void* p, long i) -> float {
        float v = isb ? bf2f(((const __hip_bfloat16*)p)[i]) : ((const float*)p)[i];
        return scrub0(v);
    };
    const long tid0   = (long)blockIdx.x * blockDim.x + threadIdx.x;
    const long stride = (long)gridDim.x * blockDim.x;

    for (long i = tid0; i < (long)VOCAB * E_DIM; i += stride)
        g_emb[i] = __float2bfloat16(ldf(emb, i));
    for (long i = tid0; i < (long)G4 * E_DIM; i += stride) {
        const int np = (int)(i >> 7), e = (int)(i & 127);
        const int g = np & 3, u = np >> 2;
        const long src = (long)(g * 128 + u) * E_DIM + e;
        g_wih[0][i] = __float2bfloat16(ldf(wih_f, src));
        g_wih[1][i] = __float2bfloat16(ldf(wih_b, src));
    }
    for (long i = tid0; i < (long)G4 * HHID; i += stride) {
        const int np = (int)(i >> 7), k = (int)(i & 127);
        const int g = np & 3, u = np >> 2;
        const long src = (long)(g * 128 + u) * HHID + k;
        g_whh2[0][i] = __float2bfloat16(ldf(whh_f, src));
        g_whh2[1][i] = __float2bfloat16(ldf(whh_b, src));
    }
    for (long i = tid0; i < G4; i += stride) {
        const int g = (int)i & 3, u = (int)i >> 2;
        const long src = g * 128 + u;
        g_bias[0][i] = ldf(bih_f, src) + ldf(bhh_f, src);
        g_bias[1][i] = ldf(bih_b, src) + ldf(bhh_b, src);
    }
    for (long i = tid0; i < T_TAG * 256; i += stride) g_wout[i] = ldf(wout, i);
    for (long i = tid0; i < T_TAG * T_TAG; i += stride) g_trans[i] = ldf(trans, i);
    for (long i = tid0; i < T_TAG; i += stride) {
        g_bout[i]  = ldf(bout, i);
        g_start[i] = ldf(startt, i);
        g_end[i]   = ldf(endt, i);
    }
    for (long i = tid0; i < (long)B_SZ * S_LEN; i += stride)
        g_maskf[i] = ldf(mask, i);
}

// -------------------------------------------------------------------------
// Fused MFMA scan, software-pipelined: during step s the block
//  (B) consumes px_s:  acc = px_s + Whh'@(h_hi+h_lo)^T     [8-chain, critical]
//  (C) produces px_{s+1} = bias + Wih'@emb_{s+1}^T          [independent of h]
//  (D) prefetches emb fragments for s+2                      [L2-resident]
// Lane (wv,quad,m16) tile t holds gates i,f,g,o (reg 0..3) of unit
// u=16wv+4t+quad, batch m16 -> c/h update fully in-lane. ONE barrier/step.
// -------------------------------------------------------------------------
__global__ __launch_bounds__(512, 1) void scan_mfma(const int* __restrict__ x)
{
    __shared__ __align__(16) unsigned short hB[2][2][16 * 16 * 8];  // 16 KB
    __shared__ int xO[S_LEN * 16];   // premultiplied emb element offsets (32 KB)

    const int bg = blockIdx.x, dir = blockIdx.y;
    const int tid  = threadIdx.x;
    const int lane = tid & 63, wv = tid >> 6;
    const int m16  = lane & 15, quad = lane >> 4;

    // persistent A fragments: Whh' + Wih' rows (lane&15 = n_local)
    bf16x8 W[4][4], V[4][4];
    f32x4 bias4[4];
    #pragma unroll
    for (int t = 0; t < 4; t++) {
        const int np = (wv * 4 + t) * 16 + m16;
        #pragma unroll
        for (int kk = 0; kk < 4; kk++) {
            W[t][kk] = *(const bf16x8*)&g_whh2[dir][(long)np * HHID + kk * 32 + quad * 8];
            V[t][kk] = *(const bf16x8*)&g_wih[dir][(long)np * E_DIM + kk * 32 + quad * 8];
        }
        const int u = 16 * wv + 4 * t + quad;
        const float4 b4 = *(const float4*)&g_bias[dir][4 * u];
        bias4[t] = (f32x4){b4.x, b4.y, b4.z, b4.w};
    }
    {   // stage premultiplied token offsets: xO[s*16+m] = x[bg*16+m][s] * E_DIM
        const bool x64 = ((x[1] | x[3] | x[5] | x[7]) == 0);
        for (int i = tid; i < S_LEN * 16; i += 512) {
            const int s = i >> 4, m = i & 15;
            const int ii = (bg * 16 + m) * S_LEN + s;
            xO[i] = (x64 ? x[2 * ii] : x[ii]) * E_DIM;
        }
    }
    for (int i = tid; i < 2 * 2 * 2048; i += 512) ((unsigned short*)hB)[i] = 0;
    float c[4] = {0.f, 0.f, 0.f, 0.f};
    __syncthreads();

    int se = dir ? (S_LEN - 1) : 0;
    const int step = dir ? -1 : 1;

    // px for step 0: bias + V@E(se0); then E <- fragments for step 1
    bf16x8 E[4];
    f32x4 px[4];
    {
        const int xo0 = xO[se * 16 + m16];
        #pragma unroll
        for (int kk = 0; kk < 4; kk++)
            E[kk] = *(const bf16x8*)&g_emb[(long)xo0 + kk * 32 + quad * 8];
        #pragma unroll
        for (int t = 0; t < 4; t++) {
            px[t] = bias4[t];
            #pragma unroll
            for (int kk = 0; kk < 4; kk++)
                px[t] = __builtin_amdgcn_mfma_f32_16x16x32_bf16(V[t][kk], E[kk], px[t], 0, 0, 0);
        }
        const int se1 = (S_LEN > 1) ? se + step : se;
        const int xo1 = xO[se1 * 16 + m16];
        #pragma unroll
        for (int kk = 0; kk < 4; kk++)
            E[kk] = *(const bf16x8*)&g_emb[(long)xo1 + kk * 32 + quad * 8];
    }

    // incremental hs store base: index ((se*16+bg)*128 + u0)*16 + m16,
    // cells at +0,+64,+128,+192; per-step delta = step*32768 floats
    float* hsp = &g_hs[dir][((long)(se * 16 + bg) * 128 + (16 * wv + quad)) * 16 + m16];
    const long hsd = (long)step * 32768;

    for (int it = 0; it < S_LEN; it++) {
        const int rd = it & 1, wr = rd ^ 1;
        const int se_next = (it + 1 < S_LEN) ? (se + step) : se;

        // (B) consume: acc = px + W@Hh + W@Hl  — the recurrent critical path
        bf16x8 Hh[4], Hl[4];
        #pragma unroll
        for (int kk = 0; kk < 4; kk++) {
            const int off = ((kk * 4 + quad) * 16 + m16) * 8;
            Hh[kk] = *(const bf16x8*)&hB[rd][0][off];
            Hl[kk] = *(const bf16x8*)&hB[rd][1][off];
        }
        f32x4 acc[4];
        #pragma unroll
        for (int t = 0; t < 4; t++) {
            acc[t] = px[t];
            #pragma unroll
            for (int kk = 0; kk < 4; kk++) {
                acc[t] = __builtin_amdgcn_mfma_f32_16x16x32_bf16(W[t][kk], Hh[kk], acc[t], 0, 0, 0);
                acc[t] = __builtin_amdgcn_mfma_f32_16x16x32_bf16(W[t][kk], Hl[kk], acc[t], 0, 0, 0);
            }
        }
        // (C) produce px for NEXT step (independent of h — fills MFMA pipe)
        #pragma unroll
        for (int t = 0; t < 4; t++) {
            px[t] = bias4[t];
            #pragma unroll
            for (int kk = 0; kk < 4; kk++)
                px[t] = __builtin_amdgcn_mfma_f32_16x16x32_bf16(V[t][kk], E[kk], px[t], 0, 0, 0);
        }
        // (D) prefetch emb fragments for step it+2 (L2-resident)
        {
            const int se2 = (it + 2 < S_LEN) ? (se_next + step) : se_next;
            const int xo2 = xO[se2 * 16 + m16];
            #pragma unroll
            for (int kk = 0; kk < 4; kk++)
                E[kk] = *(const bf16x8*)&g_emb[(long)xo2 + kk * 32 + quad * 8];
        }
        // (E) in-lane gate activation + c/h update (reg: 0=i 1=f 2=g 3=o)
        #pragma unroll
        for (int t = 0; t < 4; t++) {
            const float iv = fsig(acc[t][0]);
            const float fv = fsig(acc[t][1]);
            const float gv = ftanh(acc[t][2]);
            const float ov = fsig(acc[t][3]);
            c[t] = fv * c[t] + iv * gv;
            const float h = ov * ftanh(c[t]);
            const int u = 16 * wv + 4 * t + quad;
            const unsigned ub = __float_as_uint(h);
            const unsigned hb_ = ub >> 16;
            const float hif = __uint_as_float(ub & 0xFFFF0000u);
            const unsigned lb_ = __float_as_uint(h - hif) >> 16;
            const int ha = (u >> 3) * 128 + m16 * 8 + (u & 7);
            hB[wr][0][ha] = (unsigned short)hb_;
            hB[wr][1][ha] = (unsigned short)lb_;
            hsp[t * 64] = h;                       // +0,+64,+128,+192
        }
        __syncthreads();
        hsp += hsd;
        se = se_next;
    }
}

// -------------------------------------------------------------------------
// Bulk emission from hs layout: block = (s,bg) tile [128u x 16m], staged in
// LDS; thread (m, j<9) dots 256-k. em[r*9+j] includes bout.
// -------------------------------------------------------------------------
__global__ __launch_bounds__(256, 4) void emission_kernel()
{
    __shared__ float hfL[2048], hbL[2048];
    __shared__ float Wsh[T_TAG][256];
    __shared__ float bo[T_TAG];
    const int tid = threadIdx.x, blk = blockIdx.x;   // 0..8191 = s*16+bg
    for (int i = tid; i < T_TAG * 256; i += 256) Wsh[i >> 8][i & 255] = g_wout[i];
    if (tid < T_TAG) bo[tid] = g_bout[tid];
    const float* hf = &g_hs[0][(long)blk * 2048];
    const float* hb = &g_hs[1][(long)blk * 2048];
    for (int i = tid; i < 2048; i += 256) { hfL[i] = hf[i]; hbL[i] = hb[i]; }
    __syncthreads();

    const int m = tid & 15, j = tid >> 4;
    if (j < T_TAG) {
        float acc = bo[j];
        #pragma unroll 4
        for (int u = 0; u < 128; u++)
            acc += hfL[u * 16 + m] * Wsh[j][u] + hbL[u * 16 + m] * Wsh[j][128 + u];
        const int r = (blk >> 4) * 256 + (blk & 15) * 16 + m;   // s*256 + b
        g_em[(long)r * T_TAG + j] = scrub0(acc);
    }
}

// -------------------------------------------------------------------------
// Viterbi: 1 wave per batch element (lanes 0..8 = tags), score broadcast via
// wave shfl — NO per-step barrier. Strict-> argmax = jnp first-max.
// -------------------------------------------------------------------------
__global__ __launch_bounds__(256, 2)
void viterbi_kernel(float* __restrict__ out, int out_size)
{
    __shared__ unsigned char bp[4][S_LEN][T_TAG];
    const int wid  = threadIdx.x >> 6;
    const int lane = threadIdx.x & 63;
    const int b  = blockIdx.x * 4 + wid;
    const int jj = (lane < T_TAG) ? lane : 0;

    float tcol[T_TAG];
    #pragma unroll
    for (int i = 0; i < T_TAG; i++) tcol[i] = g_trans[i * T_TAG + jj];

    float score[T_TAG];
    {
        const float m0 = g_maskf[b * S_LEN + 0];
        #pragma unroll
        for (int i = 0; i < T_TAG; i++)
            score[i] = g_start[i] + g_em[(long)b * T_TAG + i] * m0;
    }
    float e = g_em[((long)1 * B_SZ + b) * T_TAG + jj];
    float m = g_maskf[b * S_LEN + 1];

    for (int s = 1; s < S_LEN; s++) {
        float en = 0.f, mn = 0.f;
        if (s + 1 < S_LEN) {   // prefetch next step
            en = g_em[((long)(s + 1) * B_SZ + b) * T_TAG + jj];
            mn = g_maskf[b * S_LEN + s + 1];
        }
        float best = score[0] + tcol[0];
        int arg = 0;
        #pragma unroll
        for (int i = 1; i < T_TAG; i++) {
            const float cnd = score[i] + tcol[i];
            if (cnd > best) { best = cnd; arg = i; }
        }
        float ns; int nbp;
        if (m > 0.f) { ns = best + e * m; nbp = arg; }
        else         { ns = score[jj];    nbp = jj;  }
        if (lane < T_TAG) bp[wid][s][jj] = (unsigned char)nbp;
        #pragma unroll
        for (int i = 0; i < T_TAG; i++) score[i] = __shfl(ns, i, 64);
        e = en; m = mn;
    }
    #pragma unroll
    for (int i = 0; i < T_TAG; i++) score[i] += g_end[i];

    __syncthreads();   // bp visible for backtrace

    if (lane == 0) {
        float bs = score[0]; int last = 0;
        #pragma unroll
        for (int i = 1; i < T_TAG; i++)
            if (score[i] > bs) { bs = score[i]; last = i; }
        {
            const unsigned u = __float_as_uint(bs);
            if (((u >> 23) & 0xFFu) == 0xFFu) bs = -100.f;
        }
        if ((long)B_SZ * S_LEN + b < out_size)
            out[(long)B_SZ * S_LEN + b] = bs;
        int tag = last;
        if (tag < 0) tag = 0; if (tag > 8) tag = 8;
        out[(long)b * S_LEN + (S_LEN - 1)] = (float)tag;
        for (int s2 = S_LEN - 1; s2 >= 1; s2--) {
            tag = bp[wid][s2][tag];
            if (tag < 0) tag = 0; if (tag > 8) tag = 8;
            out[(long)b * S_LEN + (s2 - 1)] = (float)tag;
        }
    }
}

// -------------------------------------------------------------------------
extern "C" void kernel_launch(void* const* d_in, const int* in_sizes, int n_in,
                              void* d_out, int out_size, void* d_ws, size_t ws_size,
                              hipStream_t stream) {
    const int* x = (const int*)d_in[0];
    float* out = (float*)d_out;

    fill_out<<<(out_size + 255) / 256, 256, 0, stream>>>(out, out_size);
    convert_kernel<<<512, 256, 0, stream>>>(
        d_in[1], d_in[2], d_in[3], d_in[4], d_in[5], d_in[6],
        d_in[7], d_in[8], d_in[9], d_in[10], d_in[11], d_in[12],
        d_in[13], d_in[14], d_in[15]);
    scan_mfma<<<dim3(16, 2), 512, 0, stream>>>(x);
    emission_kernel<<<8192, 256, 0, stream>>>();
    viterbi_kernel<<<64, 256, 0, stream>>>(out, out_size);
}